// Round 3
// baseline (282.873 us; speedup 1.0000x reference)
//
#include <hip/hip_runtime.h>
#include <stdint.h>

// VolumeRenderer: N=65536 rays, L=192 samples.
//   delta[l] = depth[l+1]-depth[l] (last = 1e10)
//   alpha = 1 - exp(-relu(sigma)*delta)
//   w     = alpha * (1 - alpha + 1e-10)     (cumprod over size-1 axis = identity)
//   color = sum_l sigmoid(rgb[l]) * w[l]     -> (N,3)
//   depth_out = sum_l w[l]*depth[l]          -> (N,1)
//
// v4: forced memory-level parallelism. v1 (scalar), v2 (LDS float4), v3
// (register pipeline) all ran 97 us @ 2.6 TB/s effective with VALUBusy 17%,
// HBM 16%, occupancy 65% -> latency-bound; compiler serialized every variant
// into load->vmcnt(0)->consume (v3's VGPR=32 proves the prefetch was sunk).
// Fix per guide T3/T4: async global_load_lds (no VGPR round-trip) + raw
// s_barrier + COUNTED s_waitcnt vmcnt(N) in inline asm, double-buffered LDS.
// Next tile's loads stay in flight across the barrier while current tile is
// computed -> >=3KB/wave continuously outstanding, ~16MB chip-wide.
//
// Geometry: tile = 4 rays = 15360 B (depth 3KB | sigma 3KB | rgb 9KB) split
// into 15 x 1KB chunks; wave w stages chunks {w, w+4, w+8, w+12<15} (waves
// 0-2: 4 chunks, wave 3: 3). Double buffer = 30720 B LDS -> 5 blocks/CU.
// Grid = 1280 persistent blocks, grid-stride over tiles (chip-wide window
// marches contiguously through memory).

constexpr int L  = 192;
constexpr int TR = 4;                       // rays per tile
constexpr int TILE_FLOATS = TR * L * 5;     // 3840 floats = 15360 B
constexpr int NCHUNK = 15;                  // 15 x 1024 B chunks
constexpr int GRID_BLOCKS = 1280;           // 5 blocks/CU x 256 CU

__device__ __forceinline__ float fast_sigmoid(float x) {
    return __builtin_amdgcn_rcpf(1.0f + __expf(-x));
}

__device__ __forceinline__ void gload16(const float* gsrc, float* ldst) {
    // async global->LDS, 16 B/lane (global_load_lds_dwordx4).
    // LDS dest is wave-uniform base + lane*16; we pass base+lane*16 per-lane
    // (consistent under both readfirstlane-base and per-lane semantics).
    __builtin_amdgcn_global_load_lds(
        (const __attribute__((address_space(1))) void*)gsrc,
        (__attribute__((address_space(3))) void*)ldst,
        16, 0, 0);
}

__global__ __launch_bounds__(256) void volrender_kernel(
    const float* __restrict__ depth, const float* __restrict__ rgb,
    const float* __restrict__ sigma, float* __restrict__ out, int n_rays)
{
    __shared__ float smem[2 * TILE_FLOATS];   // 30720 B double buffer

    const int tid  = threadIdx.x;
    const int lane = tid & 63;
    const int wave = tid >> 6;
    const int ntiles = n_rays / TR;

    // ---- stage tile -> LDS buffer buf: 3-4 async 1KB chunk loads per wave ----
    auto stage = [&](int buf, int tile) {
        float* dst0 = smem + buf * TILE_FLOATS;
        const int r0 = tile * TR;
        #pragma unroll
        for (int c = wave; c < NCHUNK; c += 4) {      // wave-uniform trip count
            const float* src;
            if (c < 3)       src = depth + r0 * L        + c * 256;
            else if (c < 6)  src = sigma + r0 * L        + (c - 3) * 256;
            else             src = rgb   + r0 * (L * 3)  + (c - 6) * 256;
            gload16(src + lane * 4, dst0 + c * 256 + lane * 4);
        }
    };

    // ---- compute one tile from LDS buffer buf (wave w = ray tile*4+w) ----
    auto compute = [&](int buf, int tile) {
        const float* base = smem + buf * TILE_FLOATS;
        const float* dp = base + wave * L;
        const float* sp = base + TR * L     + wave * L;
        const float* cp = base + 2 * TR * L + wave * (L * 3);

        float cr = 0.0f, cg = 0.0f, cb = 0.0f, dd = 0.0f;
        #pragma unroll
        for (int k = 0; k < 3; ++k) {
            const int idx = lane + 64 * k;
            const float d  = dp[idx];
            // short-circuit: dp[idx+1] not read when idx==L-1 (wave 3 edge)
            const float dl = (idx == L - 1) ? 1e10f : (dp[idx + 1] - d);
            const float s  = sp[idx];
            const float al = 1.0f - __expf(-fmaxf(s, 0.0f) * dl);
            const float wt = al * (1.0f - al + 1e-10f);
            cr += fast_sigmoid(cp[3 * idx + 0]) * wt;
            cg += fast_sigmoid(cp[3 * idx + 1]) * wt;
            cb += fast_sigmoid(cp[3 * idx + 2]) * wt;
            dd += wt * d;
        }

        #pragma unroll
        for (int off = 32; off > 0; off >>= 1) {
            cr += __shfl_xor(cr, off);
            cg += __shfl_xor(cg, off);
            cb += __shfl_xor(cb, off);
            dd += __shfl_xor(dd, off);
        }

        if (lane == 0) {
            const int ray = tile * TR + wave;
            out[ray * 3 + 0] = cr;
            out[ray * 3 + 1] = cg;
            out[ray * 3 + 2] = cb;
            out[(long long)n_rays * 3 + ray] = dd;   // depth block after color
        }
    };

    // ---- persistent double-buffered pipeline over grid-strided tiles ----
    int tile = blockIdx.x;
    if (tile >= ntiles) return;                 // block-uniform
    stage(0, tile);
    int cur = 0;

    while (true) {
        const int  nxt  = tile + gridDim.x;
        const bool more = (nxt < ntiles);       // block-uniform

        if (more) stage(cur ^ 1, nxt);          // issue next tile's async loads

        // counted wait: own current-tile loads (and older stores) done,
        // next-tile loads REMAIN IN FLIGHT across the barrier.
        if (more) {
            if (wave != 3) { asm volatile("s_waitcnt vmcnt(4)" ::: "memory"); }
            else           { asm volatile("s_waitcnt vmcnt(3)" ::: "memory"); }
        } else {
            asm volatile("s_waitcnt vmcnt(0)" ::: "memory");
        }
        __builtin_amdgcn_s_barrier();           // all waves' tile loads landed

        compute(cur, tile);

        asm volatile("" ::: "memory");
        __builtin_amdgcn_s_barrier();           // buffer free before overwrite
        asm volatile("" ::: "memory");

        if (!more) break;
        tile = nxt;
        cur ^= 1;
    }
}

extern "C" void kernel_launch(void* const* d_in, const int* in_sizes, int n_in,
                              void* d_out, int out_size, void* d_ws, size_t ws_size,
                              hipStream_t stream) {
    const float* depth = (const float*)d_in[0];
    const float* rgb   = (const float*)d_in[1];
    const float* sigma = (const float*)d_in[2];
    float* out = (float*)d_out;
    const int n_rays = in_sizes[0] / L;          // 65536
    const int ntiles = n_rays / TR;              // 16384
    int blocks = GRID_BLOCKS;
    if (blocks > ntiles) blocks = ntiles;
    volrender_kernel<<<blocks, 256, 0, stream>>>(depth, rgb, sigma, out, n_rays);
}

// Round 5
// 259.035 us; speedup vs baseline: 1.0920x; 1.0920x over previous
//
#include <hip/hip_runtime.h>

// VolumeRenderer: N=65536 rays, L=192 samples.
//   delta[l] = depth[l+1]-depth[l] (last = 1e10)
//   alpha = 1 - exp(-relu(sigma)*delta)
//   w     = alpha * (1 - alpha + 1e-10)     (cumprod over size-1 axis = identity)
//   color = sum_l sigmoid(rgb[l]) * w[l]     -> (N,3)
//   depth_out = sum_l w[l]*depth[l]          -> (N,1)
//
// v5b: non-temporal loads (compile-fixed: __builtin_nontemporal_load needs a
// native clang ext_vector_type pointer, not HIP_vector_type float4*).
// History: v1 (scalar), v2 (LDS float4), v3 (register pipeline), v4 (async
// global_load_lds + counted vmcnt, FORCED MLP) all ran 97-104 us at ~2.6 TB/s
// read with VALUBusy ~17%, zero bank conflicts, FETCH_SIZE pinned at 122.9 MB
// = exactly half the 252 MB input. Demand-side concurrency varied ~10x with
// zero throughput change => supply-side ceiling. Theory: 252 MB stream sits
// just under the 256 MB Infinity Cache -> maximal allocate/thrash (stable 50%
// hit) and the MALL fill/allocate path throttles at ~2.6 TB/s. Fix: stream
// inputs with `nt` loads to bypass cache allocation. Source = v3 verbatim
// except the load builtins (clean A/B vs v3's 99.2 us).
//
// Layout: wave = ray. Lane l (l<48) owns samples 4l..4l+3:
//   depth: 48 float4/ray, sigma: 48 float4/ray, rgb: 144 float4/ray (3/lane).
// Lanes 48-63 load clamped duplicates and are zero-masked in the reduction.

constexpr int L = 192;
constexpr int RPW = 4;   // rays per wave (software-pipelined)

typedef float vf4 __attribute__((ext_vector_type(4)));

__device__ __forceinline__ float fast_sigmoid(float x) {
    return __builtin_amdgcn_rcpf(1.0f + __expf(-x));
}

__device__ __forceinline__ vf4 ldnt4(const float* p) {
    return __builtin_nontemporal_load((const vf4*)p);
}

__global__ __launch_bounds__(256) void volrender_kernel(
    const float* __restrict__ depth, const float* __restrict__ rgb,
    const float* __restrict__ sigma, float* __restrict__ out, int n_rays)
{
    const int lane = threadIdx.x & 63;
    const int li   = (lane < 47) ? lane : 47;              // clamp idle lanes
    const int wid  = (blockIdx.x << 2) + (threadIdx.x >> 6);
    const int ray0 = wid * RPW;

    // double-buffered per-ray payload: 5 vf4 = 20 VGPRs per buffer
    vf4 d_a, s_a, c0_a, c1_a, c2_a;
    vf4 d_b, s_b, c0_b, c1_b, c2_b;

    {   // prologue: ray0 loads (all independent, issued together)
        const long long db = (long long)(ray0 * 48 + li) * 4;
        const long long cb = (long long)(ray0 * 144 + 3 * li) * 4;
        d_a  = ldnt4(depth + db);
        s_a  = ldnt4(sigma + db);
        c0_a = ldnt4(rgb + cb);
        c1_a = ldnt4(rgb + cb + 4);
        c2_a = ldnt4(rgb + cb + 8);
    }

    #pragma unroll
    for (int i = 0; i < RPW; ++i) {
        // ---- prefetch next ray before touching current ray's data ----
        if (i + 1 < RPW) {
            const int rn = ray0 + i + 1;
            const long long db = (long long)(rn * 48 + li) * 4;
            const long long cb = (long long)(rn * 144 + 3 * li) * 4;
            d_b  = ldnt4(depth + db);
            s_b  = ldnt4(sigma + db);
            c0_b = ldnt4(rgb + cb);
            c1_b = ldnt4(rgb + cb + 4);
            c2_b = ldnt4(rgb + cb + 8);
        }

        // ---- compute current ray ----
        // neighbor's first depth sample = depth[4(l+1)]
        const float dn  = __shfl(d_a.x, lane + 1);
        const float dl0 = d_a.y - d_a.x;
        const float dl1 = d_a.z - d_a.y;
        const float dl2 = d_a.w - d_a.z;
        const float dl3 = (li == 47) ? 1e10f : (dn - d_a.w);

        const float a0 = 1.0f - __expf(-fmaxf(s_a.x, 0.0f) * dl0);
        const float a1 = 1.0f - __expf(-fmaxf(s_a.y, 0.0f) * dl1);
        const float a2 = 1.0f - __expf(-fmaxf(s_a.z, 0.0f) * dl2);
        const float a3 = 1.0f - __expf(-fmaxf(s_a.w, 0.0f) * dl3);
        const float w0 = a0 * (1.0f - a0 + 1e-10f);
        const float w1 = a1 * (1.0f - a1 + 1e-10f);
        const float w2 = a2 * (1.0f - a2 + 1e-10f);
        const float w3 = a3 * (1.0f - a3 + 1e-10f);

        // rgb vf4s of lane l: c0=(r0,g0,b0,r1) c1=(g1,b1,r2,g2) c2=(b2,r3,g3,b3)
        float cr = fast_sigmoid(c0_a.x) * w0 + fast_sigmoid(c0_a.w) * w1
                 + fast_sigmoid(c1_a.z) * w2 + fast_sigmoid(c2_a.y) * w3;
        float cg = fast_sigmoid(c0_a.y) * w0 + fast_sigmoid(c1_a.x) * w1
                 + fast_sigmoid(c1_a.w) * w2 + fast_sigmoid(c2_a.z) * w3;
        float cbl= fast_sigmoid(c0_a.z) * w0 + fast_sigmoid(c1_a.y) * w1
                 + fast_sigmoid(c2_a.x) * w2 + fast_sigmoid(c2_a.w) * w3;
        float dd = d_a.x * w0 + d_a.y * w1 + d_a.z * w2 + d_a.w * w3;

        if (lane >= 48) { cr = 0.0f; cg = 0.0f; cbl = 0.0f; dd = 0.0f; }

        // ---- wave butterfly reduction ----
        #pragma unroll
        for (int off = 32; off > 0; off >>= 1) {
            cr  += __shfl_xor(cr, off);
            cg  += __shfl_xor(cg, off);
            cbl += __shfl_xor(cbl, off);
            dd  += __shfl_xor(dd, off);
        }

        if (lane == 0) {
            const int ray = ray0 + i;
            out[ray * 3 + 0] = cr;
            out[ray * 3 + 1] = cg;
            out[ray * 3 + 2] = cbl;
            out[(long long)n_rays * 3 + ray] = dd;   // depth block after color
        }

        // rotate pipeline buffers (register renaming under full unroll)
        d_a = d_b; s_a = s_b; c0_a = c0_b; c1_a = c1_b; c2_a = c2_b;
    }
}

extern "C" void kernel_launch(void* const* d_in, const int* in_sizes, int n_in,
                              void* d_out, int out_size, void* d_ws, size_t ws_size,
                              hipStream_t stream) {
    const float* depth = (const float*)d_in[0];
    const float* rgb   = (const float*)d_in[1];
    const float* sigma = (const float*)d_in[2];
    float* out = (float*)d_out;
    const int n_rays = in_sizes[0] / L;          // 65536
    const int waves  = n_rays / RPW;             // 16384 waves
    const int blocks = waves / 4;                // 4096 blocks x 256 threads
    volrender_kernel<<<blocks, 256, 0, stream>>>(depth, rgb, sigma, out, n_rays);
}